// Round 3
// baseline (79.496 us; speedup 1.0000x reference)
//
#include <hip/hip_runtime.h>
#include <math.h>

#define N_IMG 512
#define N_ANGLES 25
#define N_DET 512
#define DET_SPACING 3.0f
#define SRC_DIST 512.0f
#define DET_DIST 512.0f
#define N_SAMPLES 1024

// Reference-exact masked bilinear sample: per-corner validity, zero outside.
__device__ __forceinline__ float masked_sample(const float* __restrict__ img,
                                               float col, float row) {
    float rf = floorf(row), cf = floorf(col);
    float fr = row - rf,    fc = col - cf;
    int r0 = (int)rf, c0 = (int)cf;
    float wr0 = (r0 >=  0 && r0 < N_IMG)     ? (1.0f - fr) : 0.0f;
    float wr1 = (r0 >= -1 && r0 < N_IMG - 1) ? fr          : 0.0f;
    float wc0 = (c0 >=  0 && c0 < N_IMG)     ? (1.0f - fc) : 0.0f;
    float wc1 = (c0 >= -1 && c0 < N_IMG - 1) ? fc          : 0.0f;
    int rc0 = min(max(r0,     0), N_IMG - 1);
    int rc1 = min(max(r0 + 1, 0), N_IMG - 1);
    int cc0 = min(max(c0,     0), N_IMG - 1);
    int cc1 = min(max(c0 + 1, 0), N_IMG - 1);
    float v00 = img[(rc0 << 9) + cc0];
    float v01 = img[(rc0 << 9) + cc1];
    float v10 = img[(rc1 << 9) + cc0];
    float v11 = img[(rc1 << 9) + cc1];
    return wr0 * (wc0 * v00 + wc1 * v01) + wr1 * (wc0 * v10 + wc1 * v11);
}

// Clip [tlo,thi] to { t : lo <= v0 + t*dv <= hi }.
__device__ __forceinline__ void slab(float v0, float dv, float lo, float hi,
                                     float& tlo, float& thi) {
    if (fabsf(dv) < 1e-8f) {
        if (v0 < lo || v0 > hi) { tlo = 1.0f; thi = 0.0f; }   // empty
    } else {
        float inv = 1.0f / dv;
        float ta = (lo - v0) * inv;
        float tb = (hi - v0) * inv;
        tlo = fmaxf(tlo, fminf(ta, tb));
        thi = fminf(thi, fmaxf(ta, tb));
    }
}

__global__ __launch_bounds__(256) void fanbeam_kernel(const float* __restrict__ img,
                                                      float* __restrict__ out) {
    const int gid  = blockIdx.x * blockDim.x + threadIdx.x;
    const int ray  = gid >> 6;          // one wave64 per ray
    const int lane = threadIdx.x & 63;
    if (ray >= N_ANGLES * N_DET) return;

    const int a = ray / N_DET;
    const int d = ray - a * N_DET;

    double beta = (2.0 * M_PI) * (double)a / (double)N_ANGLES;
    float c = (float)cos(beta);
    float s = (float)sin(beta);
    float t = ((float)d - (N_DET - 1) * 0.5f) * DET_SPACING;
    float srcx = -SRC_DIST * s;
    float srcy =  SRC_DIST * c;
    float dx = (t * c + DET_DIST * s) - srcx;
    float dy = (t * s - DET_DIST * c) - srcy;
    float seg = sqrtf(dx * dx + dy * dy);

    const float half = (N_IMG - 1) * 0.5f;   // 255.5
    // col(ts) = col0 + ts*dx ; row(ts) = row0 + ts*drow
    const float col0 = srcx + half;
    const float row0 = half - srcy;
    const float drow = -dy;
    const float inv_n = 1.0f / N_SAMPLES;

    // Clip to the region where any bilinear corner can be valid:
    // contributions require col,row in (-1, 512).  Pad by epsilon + 1 sample.
    float tA = 0.0f, tB = 1.0f;
    slab(col0, dx,   -1.01f, 512.01f, tA, tB);
    slab(row0, drow, -1.01f, 512.01f, tA, tB);

    float acc = 0.0f;
    if (tA <= tB) {
        int i_lo = max(0,             (int)floorf(tA * N_SAMPLES - 0.5f) - 1);
        int i_hi = min(N_SAMPLES - 1, (int)ceilf (tB * N_SAMPLES - 0.5f) + 1);
        // Wave-uniform bounds (all lanes share the ray) -> no divergence.
        #pragma unroll 2
        for (int i = i_lo + lane; i <= i_hi; i += 64) {
            float ts  = ((float)i + 0.5f) * inv_n;
            acc += masked_sample(img, fmaf(ts, dx, col0), fmaf(ts, drow, row0));
        }
    }

    #pragma unroll
    for (int off = 32; off > 0; off >>= 1)
        acc += __shfl_down(acc, off, 64);

    if (lane == 0) out[ray] = acc * (seg * inv_n);
}

extern "C" void kernel_launch(void* const* d_in, const int* in_sizes, int n_in,
                              void* d_out, int out_size, void* d_ws, size_t ws_size,
                              hipStream_t stream) {
    const float* img = (const float*)d_in[0];
    float* out = (float*)d_out;
    const int n_rays = N_ANGLES * N_DET;              // 12800
    const int threads = 256;                          // 4 waves = 4 rays / block
    const int blocks = (n_rays * 64 + threads - 1) / threads;  // 3200
    fanbeam_kernel<<<blocks, threads, 0, stream>>>(img, out);
}